// Round 6
// baseline (210.253 us; speedup 1.0000x reference)
//
#include <hip/hip_runtime.h>

typedef __bf16 bf16x8 __attribute__((ext_vector_type(8)));
typedef float f32x4 __attribute__((ext_vector_type(4)));
typedef float f32x16 __attribute__((ext_vector_type(16)));

__device__ __forceinline__ unsigned short f2bf(float f) {
  return __builtin_bit_cast(unsigned short, (__bf16)f);
}
__device__ __forceinline__ float bfu2f(unsigned short b) {
  unsigned int u = ((unsigned int)b) << 16;
  return __builtin_bit_cast(float, u);
}
// fast silu: x * rcp(1+exp(-x)).
__device__ __forceinline__ float silu_f(float x) {
  return x * __builtin_amdgcn_rcpf(1.0f + __expf(-x));
}
__device__ __forceinline__ unsigned pk2(float a, float b) {
  return (unsigned)f2bf(a) | ((unsigned)f2bf(b) << 16);
}

// Stage a tile into LDS via global_load_lds (16B/lane). Logical layout:
// [rows][CPR*8 cols] bf16. Chunk slot s of row r holds SOURCE col block
// s^(r&SWZ); readers fetch block b at slot b^(r&SWZ) -> conflict-free b128.
template<int CPR, int NI, int SWZ>
__device__ __forceinline__ void stage16(const __bf16* __restrict__ g, int ld,
                                        __bf16* lds, int wave, int lane) {
#pragma unroll
  for (int t = 0; t < NI; ++t) {
    int cb = (wave * NI + t) * 64;
    int c = cb + lane;
    int row = c / CPR;
    int colb = (c % CPR) ^ (row & SWZ);
    __builtin_amdgcn_global_load_lds(
        (const __attribute__((address_space(1))) unsigned int*)(g + row * ld + colb * 8),
        (__attribute__((address_space(3))) unsigned int*)(lds + cb * 8),
        16, 0, 0);
  }
}

// ---------------- prep kernels ----------------

__global__ void k_tr_uvqk(const float* __restrict__ uvqk, __bf16* __restrict__ uvqkT) {
  __shared__ float tile[32][33];
  int n0 = blockIdx.x * 32, k0 = blockIdx.y * 32;
  int tx = threadIdx.x, ty = threadIdx.y;
  for (int i = ty; i < 32; i += 8)
    tile[i][tx] = uvqk[(k0 + i) * 2048 + n0 + tx];
  __syncthreads();
  for (int i = ty; i < 32; i += 8)
    uvqkT[(n0 + i) * 512 + k0 + tx] = (__bf16)tile[tx][i];
}

__global__ void k_prep(const float* __restrict__ x, __bf16* __restrict__ nx,
                       const float* __restrict__ ow, __bf16* __restrict__ owb) {
  int bid = blockIdx.x, t = threadIdx.x;
  if (bid >= 8192) {
    int i = (bid - 8192) * 128 + t;
    float4 v = ((const float4*)ow)[i];
    ushort4 o4;
    o4.x = f2bf(v.x); o4.y = f2bf(v.y); o4.z = f2bf(v.z); o4.w = f2bf(v.w);
    ((ushort4*)owb)[i] = o4;
    return;
  }
  float4 v = ((const float4*)(x + (size_t)bid * 512))[t];
  float s = v.x + v.y + v.z + v.w;
  float ss = v.x * v.x + v.y * v.y + v.z * v.z + v.w * v.w;
#pragma unroll
  for (int o = 32; o > 0; o >>= 1) { s += __shfl_down(s, o); ss += __shfl_down(ss, o); }
  __shared__ float red[4];
  if ((t & 63) == 0) { red[(t >> 6) * 2] = s; red[(t >> 6) * 2 + 1] = ss; }
  __syncthreads();
  s = red[0] + red[2]; ss = red[1] + red[3];
  float mu = s * (1.0f / 512.0f);
  float var = ss * (1.0f / 512.0f) - mu * mu;
  float rs = rsqrtf(var + 1e-6f);
  ushort4 o4;
  o4.x = f2bf((v.x - mu) * rs); o4.y = f2bf((v.y - mu) * rs);
  o4.z = f2bf((v.z - mu) * rs); o4.w = f2bf((v.w - mu) * rs);
  ((ushort4*)(nx + (size_t)bid * 512))[t] = o4;
}

// ---------------- projection GEMM: mm = silu(nx @ uvqk) ----------------
__global__ __launch_bounds__(256, 3) void k_proj(
    const __bf16* __restrict__ A, const __bf16* __restrict__ Bt,
    __bf16* __restrict__ u, __bf16* __restrict__ qn,
    __bf16* __restrict__ kn, __bf16* __restrict__ vt) {
  __shared__ __bf16 As[128 * 64], Bs[128 * 64];
  int tid = threadIdx.x, wave = tid >> 6, lane = tid & 63;
  int lr = lane & 15, lq = lane >> 4;
  int bn = blockIdx.x, bm = blockIdx.y;
  const __bf16* Ag = A + (size_t)bm * 128 * 512;
  const __bf16* Bg = Bt + (size_t)bn * 128 * 512;
  int wm = (wave >> 1) * 64, wn = (wave & 1) * 64;
  f32x4 acc[4][4] = {};
  for (int k0 = 0; k0 < 512; k0 += 64) {
    stage16<8, 4, 7>(Ag + k0, 512, As, wave, lane);
    stage16<8, 4, 7>(Bg + k0, 512, Bs, wave, lane);
    __syncthreads();
#pragma unroll
    for (int kk = 0; kk < 2; ++kk) {
      int b = kk * 4 + lq;
      bf16x8 a[4], bb[4];
#pragma unroll
      for (int i = 0; i < 4; ++i) {
        int row = wm + i * 16 + lr;
        a[i] = *(const bf16x8*)(As + row * 64 + ((b ^ (row & 7)) * 8));
      }
#pragma unroll
      for (int j = 0; j < 4; ++j) {
        int row = wn + j * 16 + lr;
        bb[j] = *(const bf16x8*)(Bs + row * 64 + ((b ^ (row & 7)) * 8));
      }
#pragma unroll
      for (int i = 0; i < 4; ++i)
#pragma unroll
        for (int j = 0; j < 4; ++j)
          acc[i][j] = __builtin_amdgcn_mfma_f32_16x16x32_bf16(a[i], bb[j], acc[i][j], 0, 0, 0);
    }
    __syncthreads();
  }
  int seg = bn >> 2;
  int cb = (bn & 3) * 128 + wn;
  int rb0 = bm * 128 + wm + lq * 4;
  if (seg == 1) {
#pragma unroll
    for (int i = 0; i < 4; ++i) {
      int rb = rb0 + i * 16;
      int b = rb >> 11, n = rb & 2047;
#pragma unroll
      for (int j = 0; j < 4; ++j) {
        int c = cb + j * 16 + lr;
        ushort4 w;
        w.x = f2bf(silu_f(acc[i][j][0]) * (1.0f / 2048.0f));
        w.y = f2bf(silu_f(acc[i][j][1]) * (1.0f / 2048.0f));
        w.z = f2bf(silu_f(acc[i][j][2]) * (1.0f / 2048.0f));
        w.w = f2bf(silu_f(acc[i][j][3]) * (1.0f / 2048.0f));
        *(ushort4*)(vt + ((size_t)(b * 512 + c)) * 2048 + n) = w;
      }
    }
  } else {
    __bf16* dst = (seg == 0) ? u : ((seg == 2) ? qn : kn);
#pragma unroll
    for (int i = 0; i < 4; ++i) {
      int rb = rb0 + i * 16;
#pragma unroll
      for (int j = 0; j < 4; ++j) {
        int c = cb + j * 16 + lr;
#pragma unroll
        for (int rg = 0; rg < 4; ++rg)
          dst[(size_t)(rb + rg) * 512 + c] = (__bf16)silu_f(acc[i][j][rg]);
      }
    }
  }
}

// ---------------- fused causal silu-attention (v4.1) ----------------
// Block (bh, p, z): q-tiles t=p then t=31-p (64 rows each); causal m-range
// of each tile split into chunks z=0/1 -> 16-17 mt units per block, 1024
// balanced blocks. 40KB LDS -> 4 blocks/CU (16 waves). Partial outputs:
// z=0 -> oa, z=1 -> ob (summed later in k_oinput).
__global__ __launch_bounds__(256, 4) void k_attn(
    const __bf16* __restrict__ qn, const __bf16* __restrict__ kn,
    const __bf16* __restrict__ vt, __bf16* __restrict__ oa,
    __bf16* __restrict__ ob) {
  __shared__ __bf16 lds[20480];  // 40 KB
  __bf16* Qs = lds;              // [64 n][64 k] 8KB
  __bf16* Kb0 = lds + 4096;      // [64 m][64 k] 8KB x2
  __bf16* Kb1 = lds + 8192;
  __bf16* Vb0 = lds + 12288;     // [64 dl][64 m] 8KB x2
  __bf16* Vb1 = lds + 16384;

  int bh = blockIdx.x, p = blockIdx.y, z = blockIdx.z;
  int b = bh >> 3, hd = bh & 7;
  int tid = threadIdx.x, wave = tid >> 6, lane = tid & 63;
  int l31 = lane & 31, lh = lane >> 5;
  int wm = (wave >> 1) * 32, wn = (wave & 1) * 32;
  const __bf16* Kg = kn + (size_t)(b * 2048) * 512 + hd * 64;
  const __bf16* Vg = vt + (size_t)(b * 512 + hd * 64) * 2048;
  __bf16* Oz = z ? ob : oa;

  for (int ph = 0; ph < 2; ++ph) {
    int t = ph ? (31 - p) : p;
    int c0 = (t + 2) >> 1;
    int mlo = z ? c0 : 0;
    int cnt = (z ? (t + 1) : c0) - mlo;
    const __bf16* Qg = qn + (size_t)(b * 2048 + t * 64) * 512 + hd * 64;
    if (ph) __syncthreads();  // epilogue LDS reads done before restaging
    stage16<8, 2, 7>(Qg, 512, Qs, wave, lane);
    if (cnt > 0) {
      stage16<8, 2, 7>(Kg + (size_t)mlo * 64 * 512, 512, Kb0, wave, lane);
      stage16<8, 2, 7>(Vg + mlo * 64, 2048, Vb0, wave, lane);
    }
    __syncthreads();

    bf16x8 qf[4];
#pragma unroll
    for (int ks = 0; ks < 4; ++ks) {
      int row = wn + l31;
      qf[ks] = *(const bf16x8*)(Qs + row * 64 + (((ks * 2 + lh) ^ (row & 7)) * 8));
    }

    f32x16 po[2] = {};

    for (int i = 0; i < cnt; ++i) {
      int mt = mlo + i;
      const __bf16* Kc = (i & 1) ? Kb1 : Kb0;
      const __bf16* Vc = (i & 1) ? Vb1 : Vb0;
      if (i + 1 < cnt) {
        __bf16* Kn_ = (i & 1) ? Kb0 : Kb1;
        __bf16* Vn_ = (i & 1) ? Vb0 : Vb1;
        stage16<8, 2, 7>(Kg + (size_t)(mt + 1) * 64 * 512, 512, Kn_, wave, lane);
        stage16<8, 2, 7>(Vg + (mt + 1) * 64, 2048, Vn_, wave, lane);
      }
      // S^T[m 32][n 32] = K . Q^T
      f32x16 s = {};
#pragma unroll
      for (int ks = 0; ks < 4; ++ks) {
        int row = wm + l31;
        bf16x8 ak = *(const bf16x8*)(Kc + row * 64 + (((ks * 2 + lh) ^ (row & 7)) * 8));
        s = __builtin_amdgcn_mfma_f32_32x32x16_bf16(ak, qf[ks], s, 0, 0, 0);
      }
      // silu + causal mask + pack + cross-half exchange -> PV B-frags
      bool diag = (mt == t);
      bool full = diag && (wm > wn + 31);
      bool dtile = diag && !full && (wm + 31 > wn);
      unsigned pk[8];
      if (full) {
#pragma unroll
        for (int q = 0; q < 8; ++q) pk[q] = 0u;
      } else {
        float vv[16];
#pragma unroll
        for (int r = 0; r < 16; ++r) {
          float xx = s[r];
          float pv = xx * __builtin_amdgcn_rcpf(1.0f + __expf(-xx));
          if (dtile) {
            int mrow = wm + 4 * lh + (r & 3) + 8 * (r >> 2);
            int ncol = wn + l31;
            if (mrow > ncol) pv = 0.0f;
          }
          vv[r] = pv;
        }
#pragma unroll
        for (int q = 0; q < 8; ++q) pk[q] = pk2(vv[2 * q], vv[2 * q + 1]);
      }
      bool lo = (lh == 0);
      unsigned xa = __shfl_xor(lo ? pk[2] : pk[0], 32);
      unsigned xb = __shfl_xor(lo ? pk[3] : pk[1], 32);
      unsigned xc = __shfl_xor(lo ? pk[6] : pk[4], 32);
      unsigned xd = __shfl_xor(lo ? pk[7] : pk[5], 32);
      union { bf16x8 v; unsigned u[4]; } f0, f1;
      f0.u[0] = lo ? pk[0] : xa;  f0.u[1] = lo ? pk[1] : xb;
      f0.u[2] = lo ? xa : pk[2];  f0.u[3] = lo ? xb : pk[3];
      f1.u[0] = lo ? pk[4] : xc;  f1.u[1] = lo ? pk[5] : xd;
      f1.u[2] = lo ? xc : pk[6];  f1.u[3] = lo ? xd : pk[7];
      bf16x8 pf[2] = { f0.v, f1.v };
      // out^T[dl][n] += V^T . P^T (K-dim = wave's 32 m at columns [wm, wm+32))
#pragma unroll
      for (int t2 = 0; t2 < 2; ++t2) {
#pragma unroll
        for (int idl = 0; idl < 2; ++idl) {
          int row = idl * 32 + l31;
          bf16x8 av = *(const bf16x8*)(Vc + row * 64 +
              ((((wm >> 3) + t2 * 2 + lh) ^ (row & 7)) * 8));
          po[idl] = __builtin_amdgcn_mfma_f32_32x32x16_bf16(av, pf[t2], po[idl], 0, 0, 0);
        }
      }
      __syncthreads();
    }

    // pair reduction: waves 2,3 (m 32..63) -> waves 0,1 (same wn)
    float* red = (float*)(Kb0);   // 4096 f32 = 16KB over K buffers (dead)
    __bf16* bo = Vb1;             // [64 n][64 dl] xor-swizzled bounce (dead)
    if (wave >= 2) {
      float* dst = red + (wave - 2) * 2048;
#pragma unroll
      for (int idl = 0; idl < 2; ++idl)
#pragma unroll
        for (int r = 0; r < 16; ++r)
          dst[(idl * 16 + r) * 64 + lane] = po[idl][r];
    }
    __syncthreads();
    if (wave < 2) {
      float* src = red + wave * 2048;
      int nrow = wn + l31;
#pragma unroll
      for (int idl = 0; idl < 2; ++idl) {
#pragma unroll
        for (int r = 0; r < 16; ++r)
          po[idl][r] += src[(idl * 16 + r) * 64 + lane];
#pragma unroll
        for (int g = 0; g < 4; ++g) {
          int dl0 = idl * 32 + g * 8 + lh * 4;
          int addr = nrow * 64 + ((((dl0 >> 3) ^ (nrow & 7)) << 3) | (dl0 & 7));
          ushort4 w;
          w.x = f2bf(po[idl][4 * g + 0]); w.y = f2bf(po[idl][4 * g + 1]);
          w.z = f2bf(po[idl][4 * g + 2]); w.w = f2bf(po[idl][4 * g + 3]);
          *(ushort4*)(bo + addr) = w;
        }
      }
    }
    __syncthreads();
    // coalesced store: Oz[b, t*64+n, hd*64 + c], 32B/thread
    {
      int n = tid >> 2, cc = (tid & 3) * 16;
      __bf16* gdst = Oz + (size_t)(b * 2048 + t * 64 + n) * 512 + hd * 64 + cc;
      int a0 = n * 64 + (((cc >> 3) ^ (n & 7)) << 3);
      int a1 = n * 64 + ((((cc >> 3) + 1) ^ (n & 7)) << 3);
      *(uint4*)(gdst) = *(const uint4*)(bo + a0);
      *(uint4*)(gdst + 8) = *(const uint4*)(bo + a1);
    }
  }
}

// o_input = u * layer_norm(oa + ob), one block (128 thr) per row
__global__ void k_oinput(const __bf16* __restrict__ oa, const __bf16* __restrict__ ob,
                         const __bf16* __restrict__ u, __bf16* __restrict__ oin) {
  int r = blockIdx.x, t = threadIdx.x;
  ushort4 a4 = ((const ushort4*)(oa + (size_t)r * 512))[t];
  ushort4 b4 = ((const ushort4*)(ob + (size_t)r * 512))[t];
  float a0 = bfu2f(a4.x) + bfu2f(b4.x), a1 = bfu2f(a4.y) + bfu2f(b4.y);
  float a2 = bfu2f(a4.z) + bfu2f(b4.z), a3 = bfu2f(a4.w) + bfu2f(b4.w);
  float s = a0 + a1 + a2 + a3;
  float ss = a0 * a0 + a1 * a1 + a2 * a2 + a3 * a3;
#pragma unroll
  for (int o = 32; o > 0; o >>= 1) { s += __shfl_down(s, o); ss += __shfl_down(ss, o); }
  __shared__ float red[4];
  if ((t & 63) == 0) { red[(t >> 6) * 2] = s; red[(t >> 6) * 2 + 1] = ss; }
  __syncthreads();
  s = red[0] + red[2]; ss = red[1] + red[3];
  float mu = s * (1.0f / 512.0f);
  float var = ss * (1.0f / 512.0f) - mu * mu;
  float rs = rsqrtf(var + 1e-6f);
  ushort4 u4 = ((const ushort4*)(u + (size_t)r * 512))[t];
  ushort4 o4;
  o4.x = f2bf(bfu2f(u4.x) * (a0 - mu) * rs);
  o4.y = f2bf(bfu2f(u4.y) * (a1 - mu) * rs);
  o4.z = f2bf(bfu2f(u4.z) * (a2 - mu) * rs);
  o4.w = f2bf(bfu2f(u4.w) * (a3 - mu) * rs);
  ((ushort4*)(oin + (size_t)r * 512))[t] = o4;
}

// out = o_in @ ow^T + bias + x.  M=8192, N=512, K=512
__global__ __launch_bounds__(256, 3) void k_out(
    const __bf16* __restrict__ A, const __bf16* __restrict__ Bt,
    const float* __restrict__ bias, const float* __restrict__ x,
    float* __restrict__ out) {
  __shared__ __bf16 As[128 * 64], Bs[128 * 64];
  int tid = threadIdx.x, wave = tid >> 6, lane = tid & 63;
  int lr = lane & 15, lq = lane >> 4;
  int bn = blockIdx.x, bm = blockIdx.y;
  const __bf16* Ag = A + (size_t)bm * 128 * 512;
  const __bf16* Bg = Bt + (size_t)bn * 128 * 512;
  int wm = (wave >> 1) * 64, wn = (wave & 1) * 64;
  f32x4 acc[4][4] = {};
  for (int k0 = 0; k0 < 512; k0 += 64) {
    stage16<8, 4, 7>(Ag + k0, 512, As, wave, lane);
    stage16<8, 4, 7>(Bg + k0, 512, Bs, wave, lane);
    __syncthreads();
#pragma unroll
    for (int kk = 0; kk < 2; ++kk) {
      int b = kk * 4 + lq;
      bf16x8 a[4], bb[4];
#pragma unroll
      for (int i = 0; i < 4; ++i) {
        int row = wm + i * 16 + lr;
        a[i] = *(const bf16x8*)(As + row * 64 + ((b ^ (row & 7)) * 8));
      }
#pragma unroll
      for (int j = 0; j < 4; ++j) {
        int row = wn + j * 16 + lr;
        bb[j] = *(const bf16x8*)(Bs + row * 64 + ((b ^ (row & 7)) * 8));
      }
#pragma unroll
      for (int i = 0; i < 4; ++i)
#pragma unroll
        for (int j = 0; j < 4; ++j)
          acc[i][j] = __builtin_amdgcn_mfma_f32_16x16x32_bf16(a[i], bb[j], acc[i][j], 0, 0, 0);
    }
    __syncthreads();
  }
  int cb = bn * 128 + wn;
  int rb0 = bm * 128 + wm + lq * 4;
#pragma unroll
  for (int j = 0; j < 4; ++j) {
    int c = cb + j * 16 + lr;
    float bv = bias[c];
#pragma unroll
    for (int i = 0; i < 4; ++i) {
      int rb = rb0 + i * 16;
#pragma unroll
      for (int rg = 0; rg < 4; ++rg) {
        size_t idx = (size_t)(rb + rg) * 512 + c;
        out[idx] = acc[i][j][rg] + bv + x[idx];
      }
    }
  }
}

extern "C" void kernel_launch(void* const* d_in, const int* in_sizes, int n_in,
                              void* d_out, int out_size, void* d_ws, size_t ws_size,
                              hipStream_t stream) {
  const float* x = (const float*)d_in[0];
  // d_in[1] = attention_mask (deterministic causal tril) -- applied analytically
  const float* uvqk = (const float*)d_in[2];
  const float* ow = (const float*)d_in[3];
  const float* obias = (const float*)d_in[4];
  float* out = (float*)d_out;

  char* w = (char*)d_ws;
  const size_t MB8 = 8u * 1024 * 1024;
  __bf16* nx    = (__bf16*)(w);             // 8 MB
  __bf16* u     = (__bf16*)(w + MB8);       // 8 MB
  __bf16* qn    = (__bf16*)(w + 2 * MB8);   // 8 MB
  __bf16* kn    = (__bf16*)(w + 3 * MB8);   // 8 MB
  __bf16* vt    = (__bf16*)(w + 4 * MB8);   // 8 MB (b, c, n) pre-scaled 1/2048
  __bf16* uvqkT = (__bf16*)(w + 5 * MB8);   // 2 MB
  __bf16* owb   = (__bf16*)(w + 5 * MB8 + 2097152);  // 0.5 MB
  __bf16* Oa    = nx;              // nx dead after k_proj
  __bf16* Ob    = (__bf16*)d_out;  // scratch in d_out; k_out overwrites later
  __bf16* o_in  = qn;              // qn dead after k_attn

  k_tr_uvqk<<<dim3(64, 16), dim3(32, 8), 0, stream>>>(uvqk, uvqkT);
  k_prep<<<8704, 128, 0, stream>>>(x, nx, ow, owb);
  k_proj<<<dim3(16, 64), 256, 0, stream>>>(nx, uvqkT, u, qn, kn, vt);
  k_attn<<<dim3(32, 16, 2), 256, 0, stream>>>(qn, kn, vt, Oa, Ob);
  k_oinput<<<8192, 128, 0, stream>>>(Oa, Ob, u, o_in);
  k_out<<<dim3(4, 64), 256, 0, stream>>>(o_in, owb, obias, x, out);
}

// Round 7
// 195.708 us; speedup vs baseline: 1.0743x; 1.0743x over previous
//
#include <hip/hip_runtime.h>

typedef __bf16 bf16x8 __attribute__((ext_vector_type(8)));
typedef float f32x4 __attribute__((ext_vector_type(4)));
typedef float f32x16 __attribute__((ext_vector_type(16)));

__device__ __forceinline__ unsigned short f2bf(float f) {
  return __builtin_bit_cast(unsigned short, (__bf16)f);
}
__device__ __forceinline__ float bfu2f(unsigned short b) {
  unsigned int u = ((unsigned int)b) << 16;
  return __builtin_bit_cast(float, u);
}
// fast silu: x * rcp(1+exp(-x)).
__device__ __forceinline__ float silu_f(float x) {
  return x * __builtin_amdgcn_rcpf(1.0f + __expf(-x));
}
__device__ __forceinline__ unsigned pk2(float a, float b) {
  return (unsigned)f2bf(a) | ((unsigned)f2bf(b) << 16);
}

// Stage a tile into LDS via global_load_lds (16B/lane). Logical layout:
// [rows][CPR*8 cols] bf16. Chunk slot s of row r holds SOURCE col block
// s^(r&SWZ); readers fetch block b at slot b^(r&SWZ) -> conflict-free b128.
template<int CPR, int NI, int SWZ>
__device__ __forceinline__ void stage16(const __bf16* __restrict__ g, int ld,
                                        __bf16* lds, int wave, int lane) {
#pragma unroll
  for (int t = 0; t < NI; ++t) {
    int cb = (wave * NI + t) * 64;
    int c = cb + lane;
    int row = c / CPR;
    int colb = (c % CPR) ^ (row & SWZ);
    __builtin_amdgcn_global_load_lds(
        (const __attribute__((address_space(1))) unsigned int*)(g + row * ld + colb * 8),
        (__attribute__((address_space(3))) unsigned int*)(lds + cb * 8),
        16, 0, 0);
  }
}

// ---------------- fused prep kernel ----------------
// blocks [0,4096): layer_norm(x)->bf16, 2 rows per 256-thr block
// blocks [4096,4352): o_weight fp32->bf16
// blocks [4352,5376): uvqk (512x2048 fp32) -> uvqkT (2048x512 bf16)
__global__ void k_prep(const float* __restrict__ x, __bf16* __restrict__ nx,
                       const float* __restrict__ ow, __bf16* __restrict__ owb,
                       const float* __restrict__ uvqk, __bf16* __restrict__ uvqkT) {
  int bid = blockIdx.x, tid = threadIdx.x;
  if (bid < 4096) {
    int t = tid & 127;             // position within row
    int r = bid * 2 + (tid >> 7);  // row
    int wave = tid >> 6;           // 0..3 (2 waves per row)
    float4 v = ((const float4*)(x + (size_t)r * 512))[t];
    float s = v.x + v.y + v.z + v.w;
    float ss = v.x * v.x + v.y * v.y + v.z * v.z + v.w * v.w;
#pragma unroll
    for (int o = 32; o > 0; o >>= 1) { s += __shfl_down(s, o); ss += __shfl_down(ss, o); }
    __shared__ float red[4][2];
    if ((tid & 63) == 0) { red[wave][0] = s; red[wave][1] = ss; }
    __syncthreads();
    int rw = (wave >> 1) * 2;
    s = red[rw][0] + red[rw + 1][0];
    ss = red[rw][1] + red[rw + 1][1];
    float mu = s * (1.0f / 512.0f);
    float var = ss * (1.0f / 512.0f) - mu * mu;
    float rs = rsqrtf(var + 1e-6f);
    ushort4 o4;
    o4.x = f2bf((v.x - mu) * rs); o4.y = f2bf((v.y - mu) * rs);
    o4.z = f2bf((v.z - mu) * rs); o4.w = f2bf((v.w - mu) * rs);
    ((ushort4*)(nx + (size_t)r * 512))[t] = o4;
  } else if (bid < 4352) {
    int i = (bid - 4096) * 256 + tid;
    float4 v = ((const float4*)ow)[i];
    ushort4 o4;
    o4.x = f2bf(v.x); o4.y = f2bf(v.y); o4.z = f2bf(v.z); o4.w = f2bf(v.w);
    ((ushort4*)owb)[i] = o4;
  } else {
    __shared__ float tile[32][33];
    int bb = bid - 4352;
    int n0 = (bb & 63) * 32, k0 = (bb >> 6) * 32;
    int tx = tid & 31, ty = tid >> 5;  // 32 x 8
    for (int i = ty; i < 32; i += 8)
      tile[i][tx] = uvqk[(k0 + i) * 2048 + n0 + tx];
    __syncthreads();
    for (int i = ty; i < 32; i += 8)
      uvqkT[(n0 + i) * 512 + k0 + tx] = (__bf16)tile[tx][i];
  }
}

// ---------------- projection GEMM: mm = silu(nx @ uvqk) ----------------
// 128x256 tile, 4 waves 2x2 (wave tile 64x128, 4x8 frags), 16x16x32 MFMA.
// 48 KB LDS, 2 blocks/CU, grid 8x64 = 512 blocks.
__global__ __launch_bounds__(256, 2) void k_proj(
    const __bf16* __restrict__ A, const __bf16* __restrict__ Bt,
    __bf16* __restrict__ u, __bf16* __restrict__ qn,
    __bf16* __restrict__ kn, __bf16* __restrict__ vt) {
  __shared__ __bf16 As[128 * 64];  // 16 KB
  __shared__ __bf16 Bs[256 * 64];  // 32 KB
  int tid = threadIdx.x, wave = tid >> 6, lane = tid & 63;
  int lr = lane & 15, lq = lane >> 4;
  int bn = blockIdx.x, bm = blockIdx.y;
  const __bf16* Ag = A + (size_t)bm * 128 * 512;
  const __bf16* Bg = Bt + (size_t)bn * 256 * 512;
  int wm = (wave >> 1) * 64, wn2 = (wave & 1) * 128;
  f32x4 acc[4][8] = {};
  for (int k0 = 0; k0 < 512; k0 += 64) {
    stage16<8, 4, 7>(Ag + k0, 512, As, wave, lane);
    stage16<8, 8, 7>(Bg + k0, 512, Bs, wave, lane);
    __syncthreads();
#pragma unroll
    for (int kk = 0; kk < 2; ++kk) {
      int b = kk * 4 + lq;
      bf16x8 a[4], bb[8];
#pragma unroll
      for (int i = 0; i < 4; ++i) {
        int row = wm + i * 16 + lr;
        a[i] = *(const bf16x8*)(As + row * 64 + ((b ^ (row & 7)) * 8));
      }
#pragma unroll
      for (int j = 0; j < 8; ++j) {
        int row = wn2 + j * 16 + lr;
        bb[j] = *(const bf16x8*)(Bs + row * 64 + ((b ^ (row & 7)) * 8));
      }
#pragma unroll
      for (int i = 0; i < 4; ++i)
#pragma unroll
        for (int j = 0; j < 8; ++j)
          acc[i][j] = __builtin_amdgcn_mfma_f32_16x16x32_bf16(a[i], bb[j], acc[i][j], 0, 0, 0);
    }
    __syncthreads();
  }
  int seg = bn >> 1;  // 256-wide block lies entirely in one 512-col segment
  int cb = (bn & 1) * 256 + wn2;
  int rb0 = bm * 128 + wm + lq * 4;
  if (seg == 1) {
#pragma unroll
    for (int i = 0; i < 4; ++i) {
      int rb = rb0 + i * 16;
      int b = rb >> 11, n = rb & 2047;
#pragma unroll
      for (int j = 0; j < 8; ++j) {
        int c = cb + j * 16 + lr;
        ushort4 w;
        w.x = f2bf(silu_f(acc[i][j][0]) * (1.0f / 2048.0f));
        w.y = f2bf(silu_f(acc[i][j][1]) * (1.0f / 2048.0f));
        w.z = f2bf(silu_f(acc[i][j][2]) * (1.0f / 2048.0f));
        w.w = f2bf(silu_f(acc[i][j][3]) * (1.0f / 2048.0f));
        *(ushort4*)(vt + ((size_t)(b * 512 + c)) * 2048 + n) = w;
      }
    }
  } else {
    __bf16* dst = (seg == 0) ? u : ((seg == 2) ? qn : kn);
#pragma unroll
    for (int i = 0; i < 4; ++i) {
      int rb = rb0 + i * 16;
#pragma unroll
      for (int j = 0; j < 8; ++j) {
        int c = cb + j * 16 + lr;
#pragma unroll
        for (int rg = 0; rg < 4; ++rg)
          dst[(size_t)(rb + rg) * 512 + c] = (__bf16)silu_f(acc[i][j][rg]);
      }
    }
  }
}

// ---------------- fused causal silu-attention (v4.1, unchanged) ----------------
__global__ __launch_bounds__(256, 4) void k_attn(
    const __bf16* __restrict__ qn, const __bf16* __restrict__ kn,
    const __bf16* __restrict__ vt, __bf16* __restrict__ oa,
    __bf16* __restrict__ ob) {
  __shared__ __bf16 lds[20480];  // 40 KB
  __bf16* Qs = lds;              // [64 n][64 k] 8KB
  __bf16* Kb0 = lds + 4096;      // [64 m][64 k] 8KB x2
  __bf16* Kb1 = lds + 8192;
  __bf16* Vb0 = lds + 12288;     // [64 dl][64 m] 8KB x2
  __bf16* Vb1 = lds + 16384;

  int bh = blockIdx.x, p = blockIdx.y, z = blockIdx.z;
  int b = bh >> 3, hd = bh & 7;
  int tid = threadIdx.x, wave = tid >> 6, lane = tid & 63;
  int l31 = lane & 31, lh = lane >> 5;
  int wm = (wave >> 1) * 32, wn = (wave & 1) * 32;
  const __bf16* Kg = kn + (size_t)(b * 2048) * 512 + hd * 64;
  const __bf16* Vg = vt + (size_t)(b * 512 + hd * 64) * 2048;
  __bf16* Oz = z ? ob : oa;

  for (int ph = 0; ph < 2; ++ph) {
    int t = ph ? (31 - p) : p;
    int c0 = (t + 2) >> 1;
    int mlo = z ? c0 : 0;
    int cnt = (z ? (t + 1) : c0) - mlo;
    const __bf16* Qg = qn + (size_t)(b * 2048 + t * 64) * 512 + hd * 64;
    if (ph) __syncthreads();  // epilogue LDS reads done before restaging
    stage16<8, 2, 7>(Qg, 512, Qs, wave, lane);
    if (cnt > 0) {
      stage16<8, 2, 7>(Kg + (size_t)mlo * 64 * 512, 512, Kb0, wave, lane);
      stage16<8, 2, 7>(Vg + mlo * 64, 2048, Vb0, wave, lane);
    }
    __syncthreads();

    bf16x8 qf[4];
#pragma unroll
    for (int ks = 0; ks < 4; ++ks) {
      int row = wn + l31;
      qf[ks] = *(const bf16x8*)(Qs + row * 64 + (((ks * 2 + lh) ^ (row & 7)) * 8));
    }

    f32x16 po[2] = {};

    for (int i = 0; i < cnt; ++i) {
      int mt = mlo + i;
      const __bf16* Kc = (i & 1) ? Kb1 : Kb0;
      const __bf16* Vc = (i & 1) ? Vb1 : Vb0;
      if (i + 1 < cnt) {
        __bf16* Kn_ = (i & 1) ? Kb0 : Kb1;
        __bf16* Vn_ = (i & 1) ? Vb0 : Vb1;
        stage16<8, 2, 7>(Kg + (size_t)(mt + 1) * 64 * 512, 512, Kn_, wave, lane);
        stage16<8, 2, 7>(Vg + (mt + 1) * 64, 2048, Vn_, wave, lane);
      }
      // S^T[m 32][n 32] = K . Q^T
      f32x16 s = {};
#pragma unroll
      for (int ks = 0; ks < 4; ++ks) {
        int row = wm + l31;
        bf16x8 ak = *(const bf16x8*)(Kc + row * 64 + (((ks * 2 + lh) ^ (row & 7)) * 8));
        s = __builtin_amdgcn_mfma_f32_32x32x16_bf16(ak, qf[ks], s, 0, 0, 0);
      }
      // silu + causal mask + pack + cross-half exchange -> PV B-frags
      bool diag = (mt == t);
      bool full = diag && (wm > wn + 31);
      bool dtile = diag && !full && (wm + 31 > wn);
      unsigned pk[8];
      if (full) {
#pragma unroll
        for (int q = 0; q < 8; ++q) pk[q] = 0u;
      } else {
        float vv[16];
#pragma unroll
        for (int r = 0; r < 16; ++r) {
          float xx = s[r];
          float pv = xx * __builtin_amdgcn_rcpf(1.0f + __expf(-xx));
          if (dtile) {
            int mrow = wm + 4 * lh + (r & 3) + 8 * (r >> 2);
            int ncol = wn + l31;
            if (mrow > ncol) pv = 0.0f;
          }
          vv[r] = pv;
        }
#pragma unroll
        for (int q = 0; q < 8; ++q) pk[q] = pk2(vv[2 * q], vv[2 * q + 1]);
      }
      bool lo = (lh == 0);
      unsigned xa = __shfl_xor(lo ? pk[2] : pk[0], 32);
      unsigned xb = __shfl_xor(lo ? pk[3] : pk[1], 32);
      unsigned xc = __shfl_xor(lo ? pk[6] : pk[4], 32);
      unsigned xd = __shfl_xor(lo ? pk[7] : pk[5], 32);
      union { bf16x8 v; unsigned u[4]; } f0, f1;
      f0.u[0] = lo ? pk[0] : xa;  f0.u[1] = lo ? pk[1] : xb;
      f0.u[2] = lo ? xa : pk[2];  f0.u[3] = lo ? xb : pk[3];
      f1.u[0] = lo ? pk[4] : xc;  f1.u[1] = lo ? pk[5] : xd;
      f1.u[2] = lo ? xc : pk[6];  f1.u[3] = lo ? xd : pk[7];
      bf16x8 pf[2] = { f0.v, f1.v };
      // out^T[dl][n] += V^T . P^T (K-dim = wave's 32 m at columns [wm, wm+32))
#pragma unroll
      for (int t2 = 0; t2 < 2; ++t2) {
#pragma unroll
        for (int idl = 0; idl < 2; ++idl) {
          int row = idl * 32 + l31;
          bf16x8 av = *(const bf16x8*)(Vc + row * 64 +
              ((((wm >> 3) + t2 * 2 + lh) ^ (row & 7)) * 8));
          po[idl] = __builtin_amdgcn_mfma_f32_32x32x16_bf16(av, pf[t2], po[idl], 0, 0, 0);
        }
      }
      __syncthreads();
    }

    // pair reduction: waves 2,3 (m 32..63) -> waves 0,1 (same wn)
    float* red = (float*)(Kb0);   // 4096 f32 = 16KB over K buffers (dead)
    __bf16* bo = Vb1;             // [64 n][64 dl] xor-swizzled bounce (dead)
    if (wave >= 2) {
      float* dst = red + (wave - 2) * 2048;
#pragma unroll
      for (int idl = 0; idl < 2; ++idl)
#pragma unroll
        for (int r = 0; r < 16; ++r)
          dst[(idl * 16 + r) * 64 + lane] = po[idl][r];
    }
    __syncthreads();
    if (wave < 2) {
      float* src = red + wave * 2048;
      int nrow = wn + l31;
#pragma unroll
      for (int idl = 0; idl < 2; ++idl) {
#pragma unroll
        for (int r = 0; r < 16; ++r)
          po[idl][r] += src[(idl * 16 + r) * 64 + lane];
#pragma unroll
        for (int g = 0; g < 4; ++g) {
          int dl0 = idl * 32 + g * 8 + lh * 4;
          int addr = nrow * 64 + ((((dl0 >> 3) ^ (nrow & 7)) << 3) | (dl0 & 7));
          ushort4 w;
          w.x = f2bf(po[idl][4 * g + 0]); w.y = f2bf(po[idl][4 * g + 1]);
          w.z = f2bf(po[idl][4 * g + 2]); w.w = f2bf(po[idl][4 * g + 3]);
          *(ushort4*)(bo + addr) = w;
        }
      }
    }
    __syncthreads();
    // coalesced store: Oz[b, t*64+n, hd*64 + c], 32B/thread
    {
      int n = tid >> 2, cc = (tid & 3) * 16;
      __bf16* gdst = Oz + (size_t)(b * 2048 + t * 64 + n) * 512 + hd * 64 + cc;
      int a0 = n * 64 + (((cc >> 3) ^ (n & 7)) << 3);
      int a1 = n * 64 + ((((cc >> 3) + 1) ^ (n & 7)) << 3);
      *(uint4*)(gdst) = *(const uint4*)(bo + a0);
      *(uint4*)(gdst + 8) = *(const uint4*)(bo + a1);
    }
  }
}

// o_input = u * layer_norm(oa + ob), one block (128 thr) per row
__global__ void k_oinput(const __bf16* __restrict__ oa, const __bf16* __restrict__ ob,
                         const __bf16* __restrict__ u, __bf16* __restrict__ oin) {
  int r = blockIdx.x, t = threadIdx.x;
  ushort4 a4 = ((const ushort4*)(oa + (size_t)r * 512))[t];
  ushort4 b4 = ((const ushort4*)(ob + (size_t)r * 512))[t];
  float a0 = bfu2f(a4.x) + bfu2f(b4.x), a1 = bfu2f(a4.y) + bfu2f(b4.y);
  float a2 = bfu2f(a4.z) + bfu2f(b4.z), a3 = bfu2f(a4.w) + bfu2f(b4.w);
  float s = a0 + a1 + a2 + a3;
  float ss = a0 * a0 + a1 * a1 + a2 * a2 + a3 * a3;
#pragma unroll
  for (int o = 32; o > 0; o >>= 1) { s += __shfl_down(s, o); ss += __shfl_down(ss, o); }
  __shared__ float red[4];
  if ((t & 63) == 0) { red[(t >> 6) * 2] = s; red[(t >> 6) * 2 + 1] = ss; }
  __syncthreads();
  s = red[0] + red[2]; ss = red[1] + red[3];
  float mu = s * (1.0f / 512.0f);
  float var = ss * (1.0f / 512.0f) - mu * mu;
  float rs = rsqrtf(var + 1e-6f);
  ushort4 u4 = ((const ushort4*)(u + (size_t)r * 512))[t];
  ushort4 o4;
  o4.x = f2bf(bfu2f(u4.x) * (a0 - mu) * rs);
  o4.y = f2bf(bfu2f(u4.y) * (a1 - mu) * rs);
  o4.z = f2bf(bfu2f(u4.z) * (a2 - mu) * rs);
  o4.w = f2bf(bfu2f(u4.w) * (a3 - mu) * rs);
  ((ushort4*)(oin + (size_t)r * 512))[t] = o4;
}

// out = o_in @ ow^T + bias + x.  M=8192, N=512, K=512.
// 64x128 tile, waves 2x2 (wave tile 32x64), grid 4x128 = 512 blocks, 24KB LDS.
__global__ __launch_bounds__(256, 4) void k_out(
    const __bf16* __restrict__ A, const __bf16* __restrict__ Bt,
    const float* __restrict__ bias, const float* __restrict__ x,
    float* __restrict__ out) {
  __shared__ __bf16 As[64 * 64];   // 8 KB
  __shared__ __bf16 Bs[128 * 64];  // 16 KB
  int tid = threadIdx.x, wave = tid >> 6, lane = tid & 63;
  int lr = lane & 15, lq = lane >> 4;
  int bn = blockIdx.x, bm = blockIdx.y;
  const __bf16* Ag = A + (size_t)bm * 64 * 512;
  const __bf16* Bg = Bt + (size_t)bn * 128 * 512;
  int wm = (wave >> 1) * 32, wn = (wave & 1) * 64;
  f32x4 acc[2][4] = {};
  for (int k0 = 0; k0 < 512; k0 += 64) {
    stage16<8, 2, 7>(Ag + k0, 512, As, wave, lane);
    stage16<8, 4, 7>(Bg + k0, 512, Bs, wave, lane);
    __syncthreads();
#pragma unroll
    for (int kk = 0; kk < 2; ++kk) {
      int b = kk * 4 + lq;
      bf16x8 a[2], bb[4];
#pragma unroll
      for (int i = 0; i < 2; ++i) {
        int row = wm + i * 16 + lr;
        a[i] = *(const bf16x8*)(As + row * 64 + ((b ^ (row & 7)) * 8));
      }
#pragma unroll
      for (int j = 0; j < 4; ++j) {
        int row = wn + j * 16 + lr;
        bb[j] = *(const bf16x8*)(Bs + row * 64 + ((b ^ (row & 7)) * 8));
      }
#pragma unroll
      for (int i = 0; i < 2; ++i)
#pragma unroll
        for (int j = 0; j < 4; ++j)
          acc[i][j] = __builtin_amdgcn_mfma_f32_16x16x32_bf16(a[i], bb[j], acc[i][j], 0, 0, 0);
    }
    __syncthreads();
  }
  int cb = bn * 128 + wn;
  int rb0 = bm * 64 + wm + lq * 4;
#pragma unroll
  for (int j = 0; j < 4; ++j) {
    int c = cb + j * 16 + lr;
    float bv = bias[c];
#pragma unroll
    for (int i = 0; i < 2; ++i) {
      int rb = rb0 + i * 16;
#pragma unroll
      for (int rg = 0; rg < 4; ++rg) {
        size_t idx = (size_t)(rb + rg) * 512 + c;
        out[idx] = acc[i][j][rg] + bv + x[idx];
      }
    }
  }
}

extern "C" void kernel_launch(void* const* d_in, const int* in_sizes, int n_in,
                              void* d_out, int out_size, void* d_ws, size_t ws_size,
                              hipStream_t stream) {
  const float* x = (const float*)d_in[0];
  // d_in[1] = attention_mask (deterministic causal tril) -- applied analytically
  const float* uvqk = (const float*)d_in[2];
  const float* ow = (const float*)d_in[3];
  const float* obias = (const float*)d_in[4];
  float* out = (float*)d_out;

  char* w = (char*)d_ws;
  const size_t MB8 = 8u * 1024 * 1024;
  __bf16* nx    = (__bf16*)(w);             // 8 MB
  __bf16* u     = (__bf16*)(w + MB8);       // 8 MB
  __bf16* qn    = (__bf16*)(w + 2 * MB8);   // 8 MB
  __bf16* kn    = (__bf16*)(w + 3 * MB8);   // 8 MB
  __bf16* vt    = (__bf16*)(w + 4 * MB8);   // 8 MB (b, c, n) pre-scaled 1/2048
  __bf16* uvqkT = (__bf16*)(w + 5 * MB8);   // 2 MB
  __bf16* owb   = (__bf16*)(w + 5 * MB8 + 2097152);  // 0.5 MB
  __bf16* Oa    = nx;              // nx dead after k_proj
  __bf16* Ob    = (__bf16*)d_out;  // scratch in d_out; k_out overwrites later
  __bf16* o_in  = qn;              // qn dead after k_attn

  k_prep<<<5376, 256, 0, stream>>>(x, nx, ow, owb, uvqk, uvqkT);
  k_proj<<<dim3(8, 64), 256, 0, stream>>>(nx, uvqkT, u, qn, kn, vt);
  k_attn<<<dim3(32, 16, 2), 256, 0, stream>>>(qn, kn, vt, Oa, Ob);
  k_oinput<<<8192, 128, 0, stream>>>(Oa, Ob, u, o_in);
  k_out<<<dim3(4, 128), 256, 0, stream>>>(o_in, owb, obias, x, out);
}